// Round 2
// baseline (567.973 us; speedup 1.0000x reference)
//
#include <hip/hip_runtime.h>
#include <hip/hip_bf16.h>
#include <stdint.h>

// ProjectiveAttention: out = softmax(h @ W @ h^T) @ h
// B=8, S=2048, D=800, all fp32 in/out.
// Strategy: bf16 hi/lo split (3-product MFMA emulation) for hW and scores,
// plain bf16 MFMA for PV. Scores materialized per batch-chunk in ws;
// softmax writes bf16 attn in place (pitch 4096 bf16 within fp32 rows).
// R2: conflict-free LDS layout [chunk][frag16][kslot8][row16] — fragment
// reads become base + lane*16 (linear); staging source address permuted to
// match (global_load_lds dest stays linear). Was 8-way conflicted.

#define BB 8
#define SS 2048
#define DD 800
#define NPAD 896          // zero-padded row count for 128-wide N tiles (7*128=896)
#define M1 (BB*SS)        // 16384

typedef unsigned short u16;
typedef __attribute__((ext_vector_type(8))) short bf16x8;
typedef __attribute__((ext_vector_type(4))) float f32x4;

__device__ __forceinline__ u16 f2bf(float x) {
    uint32_t u = __float_as_uint(x);
    uint32_t r = (u + 0x7fffu + ((u >> 16) & 1u)) >> 16;  // RTN-even
    return (u16)r;
}
__device__ __forceinline__ float bf2f(u16 h) {
    return __uint_as_float(((uint32_t)h) << 16);
}

__device__ __forceinline__ void gload16(const void* g, void* l) {
    __builtin_amdgcn_global_load_lds((__attribute__((address_space(1))) void*)g,
                                     (__attribute__((address_space(3))) void*)l,
                                     16, 0, 0);
}

// ---------------- prep kernels ----------------

// h (fp32) -> h_hi, h_lo (bf16 split), vectorized float4
__global__ __launch_bounds__(256) void hsplit_kernel(const float4* __restrict__ x,
                                                     u16* __restrict__ hi,
                                                     u16* __restrict__ lo, int n4) {
    int i = blockIdx.x * 256 + threadIdx.x;
    if (i >= n4) return;
    float4 v = x[i];
    u16 h0 = f2bf(v.x), h1 = f2bf(v.y), h2 = f2bf(v.z), h3 = f2bf(v.w);
    ushort4 hv = {h0, h1, h2, h3};
    ushort4 lv = {f2bf(v.x - bf2f(h0)), f2bf(v.y - bf2f(h1)),
                  f2bf(v.z - bf2f(h2)), f2bf(v.w - bf2f(h3))};
    *(ushort4*)(hi + (size_t)i * 4) = hv;
    *(ushort4*)(lo + (size_t)i * 4) = lv;
}

// W (fp32 [D][D]) -> Wt_hi/Wt_lo (bf16 [NPAD][D], transposed, pad rows zeroed)
__global__ __launch_bounds__(256) void wsplit_kernel(const float* __restrict__ W,
                                                     u16* __restrict__ hi,
                                                     u16* __restrict__ lo) {
    int idx = blockIdx.x * 256 + threadIdx.x;
    if (idx >= NPAD * DD) return;
    int e = idx / DD, d = idx - e * DD;
    float v = (e < DD) ? W[(size_t)d * DD + e] : 0.f;
    u16 h = f2bf(v);
    hi[idx] = h;
    lo[idx] = f2bf(v - bf2f(h));
}

// h_hi (bf16 [B][S][D]) -> hT (bf16 [B][NPAD][S], transposed per batch, pad zeroed)
__global__ void transpose_kernel(const u16* __restrict__ h_hi, u16* __restrict__ hT) {
    __shared__ u16 tile[32][33];
    int b = blockIdx.z;
    int t0 = blockIdx.x * 32, d0 = blockIdx.y * 32;
    int lx = threadIdx.x, ly = threadIdx.y;
    for (int i = ly; i < 32; i += 8) {
        int t = t0 + i, d = d0 + lx;
        tile[i][lx] = (d < DD) ? h_hi[(size_t)b * SS * DD + (size_t)t * DD + d] : (u16)0;
    }
    __syncthreads();
    for (int i = ly; i < 32; i += 8) {
        int d = d0 + i, t = t0 + lx;
        hT[(size_t)b * NPAD * SS + (size_t)d * SS + t] = tile[lx][i];
    }
}

// ---------------- softmax (one block per row, in-place fp32 -> bf16 attn) --------

__global__ __launch_bounds__(256) void softmax_kernel(float* __restrict__ scores) {
    const long row = blockIdx.x;
    float* p = scores + row * (long)SS;
    const int tid = threadIdx.x;
    const int lane = tid & 63, wid = tid >> 6;
    __shared__ float red[8];

    float v[8];
    float mx = -3.4e38f;
#pragma unroll
    for (int j = 0; j < 8; ++j) { v[j] = p[tid + 256 * j]; mx = fmaxf(mx, v[j]); }
#pragma unroll
    for (int o = 32; o; o >>= 1) mx = fmaxf(mx, __shfl_xor(mx, o, 64));
    if (lane == 0) red[wid] = mx;
    __syncthreads();
    mx = fmaxf(fmaxf(red[0], red[1]), fmaxf(red[2], red[3]));

    float sum = 0.f;
#pragma unroll
    for (int j = 0; j < 8; ++j) { v[j] = __expf(v[j] - mx); sum += v[j]; }
#pragma unroll
    for (int o = 32; o; o >>= 1) sum += __shfl_xor(sum, o, 64);
    if (lane == 0) red[4 + wid] = sum;
    __syncthreads();
    const float inv = 1.f / (red[4] + red[5] + red[6] + red[7]);

    // all reads of p[] completed before the barriers above -> safe in-place bf16 write
    u16* attn = (u16*)p;
#pragma unroll
    for (int j = 0; j < 8; ++j) attn[tid + 256 * j] = f2bf(v[j] * inv);
}

// ---------------- GEMM: C[m][n] = sum_k A[m][k] * B[n][k]  (both K-contiguous) ----
// SPLIT3: A,B given as hi/lo pairs, accumulate hi*hi + hi*lo + lo*hi
// SPLIT_OUT: write C as bf16 hi/lo split instead of fp32
// NGUARD: guard column store at Nlim (operand rows must be padded/zeroed to tile)
//
// LDS layout per operand part (4096 u16 = one 128row x 32k tile):
//   [chunk(2)][frag(4)][kslot(4)][row(16)][8 u16]
// chunk = 64-row half, frag = 16-row group within chunk, kslot = 8-k group.
// A wave's MFMA fragment read = region_base + lane*16 bytes (conflict-free);
// global_load_lds writes base + lane*16, so the staging *source* address is
// permuted to match: row = wid*16 + (lane&15), k = (lane>>4)*8.

template <int SPLIT3, int SPLIT_OUT, int NGUARD>
__global__ __launch_bounds__(256) void gemm_kernel(
    const u16* __restrict__ Ahi, const u16* __restrict__ Alo, long sA, int lda,
    const u16* __restrict__ Bhi, const u16* __restrict__ Blo, long sB, int ldb,
    float* __restrict__ C, u16* __restrict__ Chi, u16* __restrict__ Clo,
    long sC, int ldc, int Nlim, int ksteps) {
    constexpr int PARTS = SPLIT3 ? 2 : 1;
    __shared__ __align__(16) u16 lsA[PARTS * 4096];
    __shared__ __align__(16) u16 lsB[PARTS * 4096];

    const int tid = threadIdx.x;
    const int lane = tid & 63, wid = tid >> 6;
    const int zb = blockIdx.z;
    const int m0 = blockIdx.x * 128, n0 = blockIdx.y * 128;

    const u16* Ah = Ahi + (long)zb * sA;
    const u16* Bh = Bhi + (long)zb * sB;
    const u16* Al = SPLIT3 ? (Alo + (long)zb * sA) : nullptr;
    const u16* Bl = SPLIT3 ? (Blo + (long)zb * sB) : nullptr;

    // staging source coords (permuted to match linear LDS dest = base + lane*16)
    const int srow = wid * 16 + (lane & 15);
    const int scol = (lane >> 4) * 8;
    const int wm = wid >> 1, wn = wid & 1;

    // fragment read bases (u16 index): chunk w + lane*8, + f*512 per fragment
    const int abase = wm * 2048 + lane * 8;
    const int bbase = wn * 2048 + lane * 8;

    f32x4 acc[4][4];
#pragma unroll
    for (int i = 0; i < 4; ++i)
#pragma unroll
        for (int j = 0; j < 4; ++j) acc[i][j] = (f32x4){0.f, 0.f, 0.f, 0.f};

    char* lA = (char*)lsA + wid * 1024;  // wave-uniform LDS staging base
    char* lB = (char*)lsB + wid * 1024;

    for (int ks = 0; ks < ksteps; ++ks) {
        const int k0 = ks * 32;
        __syncthreads();  // previous iter's ds_reads complete before overwrite
        {
            const u16* g = Ah + (long)(m0 + srow) * lda + (k0 + scol);
            gload16(g, lA);
            gload16(g + (long)64 * lda, lA + 4096);
            const u16* gb = Bh + (long)(n0 + srow) * ldb + (k0 + scol);
            gload16(gb, lB);
            gload16(gb + (long)64 * ldb, lB + 4096);
            if (SPLIT3) {
                const u16* g2 = Al + (long)(m0 + srow) * lda + (k0 + scol);
                gload16(g2, lA + 8192);
                gload16(g2 + (long)64 * lda, lA + 12288);
                const u16* gb2 = Bl + (long)(n0 + srow) * ldb + (k0 + scol);
                gload16(gb2, lB + 8192);
                gload16(gb2 + (long)64 * ldb, lB + 12288);
            }
        }
        __syncthreads();  // vmcnt(0) drained by compiler before barrier

        bf16x8 ah[4], bh[4], al[4], bl[4];
#pragma unroll
        for (int f = 0; f < 4; ++f) {
            ah[f] = *(const bf16x8*)&lsA[abase + f * 512];
            bh[f] = *(const bf16x8*)&lsB[bbase + f * 512];
            if (SPLIT3) {
                al[f] = *(const bf16x8*)&lsA[4096 + abase + f * 512];
                bl[f] = *(const bf16x8*)&lsB[4096 + bbase + f * 512];
            }
        }
#pragma unroll
        for (int i = 0; i < 4; ++i)
#pragma unroll
            for (int j = 0; j < 4; ++j) {
                acc[i][j] = __builtin_amdgcn_mfma_f32_16x16x32_bf16(ah[i], bh[j], acc[i][j], 0, 0, 0);
                if (SPLIT3) {
                    acc[i][j] = __builtin_amdgcn_mfma_f32_16x16x32_bf16(ah[i], bl[j], acc[i][j], 0, 0, 0);
                    acc[i][j] = __builtin_amdgcn_mfma_f32_16x16x32_bf16(al[i], bh[j], acc[i][j], 0, 0, 0);
                }
            }
    }

    // epilogue: C/D layout col=lane&15, row=(lane>>4)*4+reg  [m89-verified]
    const int crow = m0 + wm * 64 + (lane >> 4) * 4;
    const int ccol = n0 + wn * 64 + (lane & 15);
#pragma unroll
    for (int i = 0; i < 4; ++i) {
#pragma unroll
        for (int j = 0; j < 4; ++j) {
            const int nn = ccol + j * 16;
            if (NGUARD && nn >= Nlim) continue;
#pragma unroll
            for (int r = 0; r < 4; ++r) {
                const int mm = crow + i * 16 + r;
                const long off = (long)zb * sC + (long)mm * ldc + nn;
                if (SPLIT_OUT) {
                    float v = acc[i][j][r];
                    u16 hh = f2bf(v);
                    Chi[off] = hh;
                    Clo[off] = f2bf(v - bf2f(hh));
                } else {
                    C[off] = acc[i][j][r];
                }
            }
        }
    }
}

// ---------------- host ----------------

extern "C" void kernel_launch(void* const* d_in, const int* in_sizes, int n_in,
                              void* d_out, int out_size, void* d_ws, size_t ws_size,
                              hipStream_t stream) {
    const float* h = (const float*)d_in[0];
    const float* W = (const float*)d_in[1];
    float* out = (float*)d_out;

    char* ws = (char*)d_ws;
    size_t off = 0;
    auto alloc = [&](size_t bytes) -> void* {
        void* p = ws + off;
        off += (bytes + 255) & ~(size_t)255;
        return p;
    };
    const size_t MD = (size_t)BB * SS * DD;
    u16* h_hi  = (u16*)alloc(MD * 2);
    u16* h_lo  = (u16*)alloc(MD * 2);
    u16* hW_hi = (u16*)alloc(MD * 2);
    u16* hW_lo = (u16*)alloc(MD * 2);
    u16* hT    = (u16*)alloc((size_t)BB * NPAD * SS * 2);
    u16* Wt_hi = (u16*)alloc((size_t)NPAD * DD * 2);
    u16* Wt_lo = (u16*)alloc((size_t)NPAD * DD * 2);

    size_t remain = (ws_size > off) ? (ws_size - off) : 0;
    const size_t batch_bytes = (size_t)SS * SS * 4;
    int nb = (int)(remain / batch_bytes);
    if (nb < 1) nb = 1;
    if (nb > BB) nb = BB;
    float* scores = (float*)alloc((size_t)nb * batch_bytes);

    // prep: splits + transpose
    hsplit_kernel<<<dim3((unsigned)(MD / 4 / 256)), dim3(256), 0, stream>>>(
        (const float4*)h, h_hi, h_lo, (int)(MD / 4));
    wsplit_kernel<<<dim3((NPAD * DD + 255) / 256), dim3(256), 0, stream>>>(W, Wt_hi, Wt_lo);
    transpose_kernel<<<dim3(SS / 32, NPAD / 32, BB), dim3(32, 8), 0, stream>>>(h_hi, hT);

    // GEMM1: hW = h @ W   (M=16384, N=800 -> 7 tiles, K=800 -> 25 steps), split-out
    gemm_kernel<1, 1, 1><<<dim3(M1 / 128, 7, 1), dim3(256), 0, stream>>>(
        h_hi, h_lo, 0L, DD,
        Wt_hi, Wt_lo, 0L, DD,
        (float*)nullptr, hW_hi, hW_lo, 0L, DD, DD, DD / 32);

    for (int b0 = 0; b0 < BB; b0 += nb) {
        int nbc = (BB - b0 < nb) ? (BB - b0) : nb;
        // GEMM2: scores = hW @ h^T  (per-batch M=N=2048, K=800)
        gemm_kernel<1, 0, 0><<<dim3(SS / 128, SS / 128, nbc), dim3(256), 0, stream>>>(
            hW_hi + (size_t)b0 * SS * DD, hW_lo + (size_t)b0 * SS * DD, (long)SS * DD, DD,
            h_hi + (size_t)b0 * SS * DD, h_lo + (size_t)b0 * SS * DD, (long)SS * DD, DD,
            scores, (u16*)nullptr, (u16*)nullptr, (long)SS * SS, SS, SS, DD / 32);
        // softmax rows, writes bf16 attn in place (pitch 4096 bf16 per row)
        softmax_kernel<<<dim3(nbc * SS), dim3(256), 0, stream>>>(scores);
        // PV: out = attn @ h   (A = attn bf16 pitch 4096, B = hT, M=2048,N=800,K=2048)
        gemm_kernel<0, 0, 1><<<dim3(SS / 128, 7, nbc), dim3(256), 0, stream>>>(
            (const u16*)scores, (const u16*)nullptr, (long)SS * SS * 2, SS * 2,
            hT + (size_t)b0 * NPAD * SS, (const u16*)nullptr, (long)NPAD * SS, SS,
            out + (size_t)b0 * SS * DD, (u16*)nullptr, (u16*)nullptr,
            (long)SS * DD, DD, DD, SS / 32);
    }
}

// Round 3
// 549.668 us; speedup vs baseline: 1.0333x; 1.0333x over previous
//
#include <hip/hip_runtime.h>
#include <hip/hip_bf16.h>
#include <stdint.h>

// ProjectiveAttention: out = softmax(h @ W @ h^T) @ h
// B=8, S=2048, D=800, all fp32 in/out.
// Strategy: bf16 hi/lo split (3-product MFMA emulation) for hW and scores,
// plain bf16 MFMA for PV. Scores materialized in ws; softmax writes bf16 attn
// in place (pitch 4096 bf16 within fp32 rows).
// R2: conflict-free LDS layout [chunk][frag16][kslot8][row16] (conflicts 1.15e7 -> 0).
// R3: prefetch double-buffered K-loop with counted vmcnt (T3+T4 minimal form):
//     issue tile t+1 stages before computing tile t; s_waitcnt vmcnt(8/4), never 0,
//     raw s_barrier (NOT __syncthreads which drains vmcnt); setprio around MFMA (T5).

#define BB 8
#define SS 2048
#define DD 800
#define NPAD 896          // zero-padded row count for 128-wide N tiles (7*128=896)
#define M1 (BB*SS)        // 16384

typedef unsigned short u16;
typedef __attribute__((ext_vector_type(8))) short bf16x8;
typedef __attribute__((ext_vector_type(4))) float f32x4;

__device__ __forceinline__ u16 f2bf(float x) {
    uint32_t u = __float_as_uint(x);
    uint32_t r = (u + 0x7fffu + ((u >> 16) & 1u)) >> 16;  // RTN-even
    return (u16)r;
}
__device__ __forceinline__ float bf2f(u16 h) {
    return __uint_as_float(((uint32_t)h) << 16);
}

__device__ __forceinline__ void gload16(const void* g, void* l) {
    __builtin_amdgcn_global_load_lds((__attribute__((address_space(1))) void*)g,
                                     (__attribute__((address_space(3))) void*)l,
                                     16, 0, 0);
}

// ---------------- prep kernels ----------------

// h (fp32) -> h_hi, h_lo (bf16 split), vectorized float4
__global__ __launch_bounds__(256) void hsplit_kernel(const float4* __restrict__ x,
                                                     u16* __restrict__ hi,
                                                     u16* __restrict__ lo, int n4) {
    int i = blockIdx.x * 256 + threadIdx.x;
    if (i >= n4) return;
    float4 v = x[i];
    u16 h0 = f2bf(v.x), h1 = f2bf(v.y), h2 = f2bf(v.z), h3 = f2bf(v.w);
    ushort4 hv = {h0, h1, h2, h3};
    ushort4 lv = {f2bf(v.x - bf2f(h0)), f2bf(v.y - bf2f(h1)),
                  f2bf(v.z - bf2f(h2)), f2bf(v.w - bf2f(h3))};
    *(ushort4*)(hi + (size_t)i * 4) = hv;
    *(ushort4*)(lo + (size_t)i * 4) = lv;
}

// W (fp32 [D][D]) -> Wt_hi/Wt_lo (bf16 [NPAD][D], transposed, pad rows zeroed)
__global__ __launch_bounds__(256) void wsplit_kernel(const float* __restrict__ W,
                                                     u16* __restrict__ hi,
                                                     u16* __restrict__ lo) {
    int idx = blockIdx.x * 256 + threadIdx.x;
    if (idx >= NPAD * DD) return;
    int e = idx / DD, d = idx - e * DD;
    float v = (e < DD) ? W[(size_t)d * DD + e] : 0.f;
    u16 h = f2bf(v);
    hi[idx] = h;
    lo[idx] = f2bf(v - bf2f(h));
}

// h_hi (bf16 [B][S][D]) -> hT (bf16 [B][NPAD][S], transposed per batch, pad zeroed)
__global__ void transpose_kernel(const u16* __restrict__ h_hi, u16* __restrict__ hT) {
    __shared__ u16 tile[32][33];
    int b = blockIdx.z;
    int t0 = blockIdx.x * 32, d0 = blockIdx.y * 32;
    int lx = threadIdx.x, ly = threadIdx.y;
    for (int i = ly; i < 32; i += 8) {
        int t = t0 + i, d = d0 + lx;
        tile[i][lx] = (d < DD) ? h_hi[(size_t)b * SS * DD + (size_t)t * DD + d] : (u16)0;
    }
    __syncthreads();
    for (int i = ly; i < 32; i += 8) {
        int d = d0 + i, t = t0 + lx;
        hT[(size_t)b * NPAD * SS + (size_t)d * SS + t] = tile[lx][i];
    }
}

// ---------------- softmax (one block per row, in-place fp32 -> bf16 attn) --------

__global__ __launch_bounds__(256) void softmax_kernel(float* __restrict__ scores) {
    const long row = blockIdx.x;
    float* p = scores + row * (long)SS;
    const int tid = threadIdx.x;
    const int lane = tid & 63, wid = tid >> 6;
    __shared__ float red[8];

    float v[8];
    float mx = -3.4e38f;
#pragma unroll
    for (int j = 0; j < 8; ++j) { v[j] = p[tid + 256 * j]; mx = fmaxf(mx, v[j]); }
#pragma unroll
    for (int o = 32; o; o >>= 1) mx = fmaxf(mx, __shfl_xor(mx, o, 64));
    if (lane == 0) red[wid] = mx;
    __syncthreads();
    mx = fmaxf(fmaxf(red[0], red[1]), fmaxf(red[2], red[3]));

    float sum = 0.f;
#pragma unroll
    for (int j = 0; j < 8; ++j) { v[j] = __expf(v[j] - mx); sum += v[j]; }
#pragma unroll
    for (int o = 32; o; o >>= 1) sum += __shfl_xor(sum, o, 64);
    if (lane == 0) red[4 + wid] = sum;
    __syncthreads();
    const float inv = 1.f / (red[4] + red[5] + red[6] + red[7]);

    // all reads of p[] completed before the barriers above -> safe in-place bf16 write
    u16* attn = (u16*)p;
#pragma unroll
    for (int j = 0; j < 8; ++j) attn[tid + 256 * j] = f2bf(v[j] * inv);
}

// ---------------- GEMM: C[m][n] = sum_k A[m][k] * B[n][k]  (both K-contiguous) ----
// SPLIT3: A,B given as hi/lo pairs, accumulate hi*hi + hi*lo + lo*hi
// SPLIT_OUT: write C as bf16 hi/lo split instead of fp32
// NGUARD: guard column store at Nlim (operand rows must be padded/zeroed to tile)
//
// LDS layout per operand part (4096 u16 = one 128row x 32k tile):
//   [chunk(2)][frag(4)][kslot(4)][row(16)][8 u16]
// Fragment read = region_base + lane*16 B (conflict-free, verified R2: conflicts=0);
// staging source address permuted to match linear global_load_lds dest.
//
// K-loop: double-buffered prefetch pipeline. STAGE(t+1) issued before compute(t);
// per-wave counted s_waitcnt vmcnt(8 split / 4 plain) keeps next tile's loads in
// flight across the barrier; raw s_barrier (no vmcnt(0) drain). 2 barriers/iter.

template <int SPLIT3, int SPLIT_OUT, int NGUARD>
__global__ __launch_bounds__(256) void gemm_kernel(
    const u16* __restrict__ Ahi, const u16* __restrict__ Alo, long sA, int lda,
    const u16* __restrict__ Bhi, const u16* __restrict__ Blo, long sB, int ldb,
    float* __restrict__ C, u16* __restrict__ Chi, u16* __restrict__ Clo,
    long sC, int ldc, int Nlim, int ksteps) {
    constexpr int PARTS = SPLIT3 ? 2 : 1;
    __shared__ __align__(16) u16 lsA[2][PARTS * 4096];
    __shared__ __align__(16) u16 lsB[2][PARTS * 4096];

    const int tid = threadIdx.x;
    const int lane = tid & 63, wid = tid >> 6;
    const int zb = blockIdx.z;
    const int m0 = blockIdx.x * 128, n0 = blockIdx.y * 128;

    const u16* Ah = Ahi + (long)zb * sA;
    const u16* Bh = Bhi + (long)zb * sB;
    const u16* Al = SPLIT3 ? (Alo + (long)zb * sA) : nullptr;
    const u16* Bl = SPLIT3 ? (Blo + (long)zb * sB) : nullptr;

    // staging source coords (permuted to match linear LDS dest = base + lane*16)
    const int srow = wid * 16 + (lane & 15);
    const int scol = (lane >> 4) * 8;
    const int wm = wid >> 1, wn = wid & 1;

    // fragment read bases (u16 index): chunk wm/wn + lane*8, + f*512 per fragment
    const int abase = wm * 2048 + lane * 8;
    const int bbase = wn * 2048 + lane * 8;

    f32x4 acc[4][4];
#pragma unroll
    for (int i = 0; i < 4; ++i)
#pragma unroll
        for (int j = 0; j < 4; ++j) acc[i][j] = (f32x4){0.f, 0.f, 0.f, 0.f};

    auto STAGE = [&](int ks, int buf) {
        const int k0 = ks * 32;
        char* lA = (char*)(&lsA[buf][0]) + wid * 1024;  // wave-uniform LDS base
        char* lB = (char*)(&lsB[buf][0]) + wid * 1024;
        const u16* g = Ah + (long)(m0 + srow) * lda + (k0 + scol);
        gload16(g, lA);
        gload16(g + (long)64 * lda, lA + 4096);
        const u16* gb = Bh + (long)(n0 + srow) * ldb + (k0 + scol);
        gload16(gb, lB);
        gload16(gb + (long)64 * ldb, lB + 4096);
        if (SPLIT3) {
            const u16* g2 = Al + (long)(m0 + srow) * lda + (k0 + scol);
            gload16(g2, lA + 8192);
            gload16(g2 + (long)64 * lda, lA + 12288);
            const u16* gb2 = Bl + (long)(n0 + srow) * ldb + (k0 + scol);
            gload16(gb2, lB + 8192);
            gload16(gb2 + (long)64 * ldb, lB + 12288);
        }
    };

    STAGE(0, 0);

    for (int ks = 0; ks < ksteps; ++ks) {
        const int cur = ks & 1;
        if (ks + 1 < ksteps) {
            STAGE(ks + 1, cur ^ 1);  // buf[cur^1] readers finished at prev tail barrier
            // wait for buf[cur]'s loads only; keep the 8/4 just-issued in flight
            if constexpr (SPLIT3) {
                asm volatile("s_waitcnt vmcnt(8)" ::: "memory");
            } else {
                asm volatile("s_waitcnt vmcnt(4)" ::: "memory");
            }
        } else {
            asm volatile("s_waitcnt vmcnt(0)" ::: "memory");
        }
        __builtin_amdgcn_sched_barrier(0);
        __builtin_amdgcn_s_barrier();   // cross-wave: all DMA writes to buf[cur] visible
        __builtin_amdgcn_sched_barrier(0);

        bf16x8 ah[4], bh[4], al[4], bl[4];
#pragma unroll
        for (int f = 0; f < 4; ++f) {
            ah[f] = *(const bf16x8*)&lsA[cur][abase + f * 512];
            bh[f] = *(const bf16x8*)&lsB[cur][bbase + f * 512];
            if (SPLIT3) {
                al[f] = *(const bf16x8*)&lsA[cur][4096 + abase + f * 512];
                bl[f] = *(const bf16x8*)&lsB[cur][4096 + bbase + f * 512];
            }
        }
        __builtin_amdgcn_s_setprio(1);
#pragma unroll
        for (int i = 0; i < 4; ++i)
#pragma unroll
            for (int j = 0; j < 4; ++j) {
                acc[i][j] = __builtin_amdgcn_mfma_f32_16x16x32_bf16(ah[i], bh[j], acc[i][j], 0, 0, 0);
                if (SPLIT3) {
                    acc[i][j] = __builtin_amdgcn_mfma_f32_16x16x32_bf16(ah[i], bl[j], acc[i][j], 0, 0, 0);
                    acc[i][j] = __builtin_amdgcn_mfma_f32_16x16x32_bf16(al[i], bh[j], acc[i][j], 0, 0, 0);
                }
            }
        __builtin_amdgcn_s_setprio(0);

        __builtin_amdgcn_sched_barrier(0);
        __builtin_amdgcn_s_barrier();   // all waves done reading buf[cur] before overwrite
        __builtin_amdgcn_sched_barrier(0);
    }

    // epilogue: C/D layout col=lane&15, row=(lane>>4)*4+reg  [m89-verified]
    const int crow = m0 + wm * 64 + (lane >> 4) * 4;
    const int ccol = n0 + wn * 64 + (lane & 15);
#pragma unroll
    for (int i = 0; i < 4; ++i) {
#pragma unroll
        for (int j = 0; j < 4; ++j) {
            const int nn = ccol + j * 16;
            if (NGUARD && nn >= Nlim) continue;
#pragma unroll
            for (int r = 0; r < 4; ++r) {
                const int mm = crow + i * 16 + r;
                const long off = (long)zb * sC + (long)mm * ldc + nn;
                if (SPLIT_OUT) {
                    float v = acc[i][j][r];
                    u16 hh = f2bf(v);
                    Chi[off] = hh;
                    Clo[off] = f2bf(v - bf2f(hh));
                } else {
                    C[off] = acc[i][j][r];
                }
            }
        }
    }
}

// ---------------- host ----------------

extern "C" void kernel_launch(void* const* d_in, const int* in_sizes, int n_in,
                              void* d_out, int out_size, void* d_ws, size_t ws_size,
                              hipStream_t stream) {
    const float* h = (const float*)d_in[0];
    const float* W = (const float*)d_in[1];
    float* out = (float*)d_out;

    char* ws = (char*)d_ws;
    size_t off = 0;
    auto alloc = [&](size_t bytes) -> void* {
        void* p = ws + off;
        off += (bytes + 255) & ~(size_t)255;
        return p;
    };
    const size_t MD = (size_t)BB * SS * DD;
    u16* h_hi  = (u16*)alloc(MD * 2);
    u16* h_lo  = (u16*)alloc(MD * 2);
    u16* hW_hi = (u16*)alloc(MD * 2);
    u16* hW_lo = (u16*)alloc(MD * 2);
    u16* hT    = (u16*)alloc((size_t)BB * NPAD * SS * 2);
    u16* Wt_hi = (u16*)alloc((size_t)NPAD * DD * 2);
    u16* Wt_lo = (u16*)alloc((size_t)NPAD * DD * 2);

    size_t remain = (ws_size > off) ? (ws_size - off) : 0;
    const size_t batch_bytes = (size_t)SS * SS * 4;
    int nb = (int)(remain / batch_bytes);
    if (nb < 1) nb = 1;
    if (nb > BB) nb = BB;
    float* scores = (float*)alloc((size_t)nb * batch_bytes);

    // prep: splits + transpose
    hsplit_kernel<<<dim3((unsigned)(MD / 4 / 256)), dim3(256), 0, stream>>>(
        (const float4*)h, h_hi, h_lo, (int)(MD / 4));
    wsplit_kernel<<<dim3((NPAD * DD + 255) / 256), dim3(256), 0, stream>>>(W, Wt_hi, Wt_lo);
    transpose_kernel<<<dim3(SS / 32, NPAD / 32, BB), dim3(32, 8), 0, stream>>>(h_hi, hT);

    // GEMM1: hW = h @ W   (M=16384, N=800 -> 7 tiles, K=800 -> 25 steps), split-out
    gemm_kernel<1, 1, 1><<<dim3(M1 / 128, 7, 1), dim3(256), 0, stream>>>(
        h_hi, h_lo, 0L, DD,
        Wt_hi, Wt_lo, 0L, DD,
        (float*)nullptr, hW_hi, hW_lo, 0L, DD, DD, DD / 32);

    for (int b0 = 0; b0 < BB; b0 += nb) {
        int nbc = (BB - b0 < nb) ? (BB - b0) : nb;
        // GEMM2: scores = hW @ h^T  (per-batch M=N=2048, K=800)
        gemm_kernel<1, 0, 0><<<dim3(SS / 128, SS / 128, nbc), dim3(256), 0, stream>>>(
            hW_hi + (size_t)b0 * SS * DD, hW_lo + (size_t)b0 * SS * DD, (long)SS * DD, DD,
            h_hi + (size_t)b0 * SS * DD, h_lo + (size_t)b0 * SS * DD, (long)SS * DD, DD,
            scores, (u16*)nullptr, (u16*)nullptr, (long)SS * SS, SS, SS, DD / 32);
        // softmax rows, writes bf16 attn in place (pitch 4096 bf16 per row)
        softmax_kernel<<<dim3(nbc * SS), dim3(256), 0, stream>>>(scores);
        // PV: out = attn @ h   (A = attn bf16 pitch 4096, B = hT, M=2048,N=800,K=2048)
        gemm_kernel<0, 0, 1><<<dim3(SS / 128, 7, nbc), dim3(256), 0, stream>>>(
            (const u16*)scores, (const u16*)nullptr, (long)SS * SS * 2, SS * 2,
            hT + (size_t)b0 * NPAD * SS, (const u16*)nullptr, (long)NPAD * SS, SS,
            out + (size_t)b0 * SS * DD, (u16*)nullptr, (u16*)nullptr,
            (long)SS * DD, DD, DD, SS / 32);
    }
}

// Round 4
// 453.057 us; speedup vs baseline: 1.2536x; 1.2132x over previous
//
#include <hip/hip_runtime.h>
#include <hip/hip_bf16.h>
#include <stdint.h>

// ProjectiveAttention: out = softmax(h @ W @ h^T) @ h
// B=8, S=2048, D=800, all fp32 in/out.
// R4: 8-phase-class deep-pipelined GEMM template (256x256xBK64, 8 waves,
// 128KB LDS dyn) with counted vmcnt fences (never 0 mid-loop), setprio,
// conflict-free subtiled LDS, XCD-bijective swizzle. Split3 bf16 emulation
// expressed as K-extended plain GEMM (K' = 3K: hi*hi, hi*lo, lo*hi tiles).
// PV uses BM=128 variant (2 phases/K-tile) for occupancy at 4-batch chunks.

#define BB 8
#define SS 2048
#define DD 800
#define KP 832            // K padded to 13*64
#define M1 (BB*SS)        // 16384

typedef unsigned short u16;
typedef __attribute__((ext_vector_type(8))) short bf16x8;
typedef __attribute__((ext_vector_type(4))) float f32x4;

#define MFMA16(A, B, C) __builtin_amdgcn_mfma_f32_16x16x32_bf16(A, B, C, 0, 0, 0)
#define VMF(N) asm volatile("s_waitcnt vmcnt(" #N ")" ::: "memory")

__device__ __forceinline__ u16 f2bf(float x) {
    uint32_t u = __float_as_uint(x);
    uint32_t r = (u + 0x7fffu + ((u >> 16) & 1u)) >> 16;  // RTN-even
    return (u16)r;
}
__device__ __forceinline__ float bf2f(u16 h) {
    return __uint_as_float(((uint32_t)h) << 16);
}
__device__ __forceinline__ void gload16(const void* g, void* l) {
    __builtin_amdgcn_global_load_lds((__attribute__((address_space(1))) void*)g,
                                     (__attribute__((address_space(3))) void*)l,
                                     16, 0, 0);
}
__device__ __forceinline__ void barrier_pin() {
    __builtin_amdgcn_sched_barrier(0);
    __builtin_amdgcn_s_barrier();
    __builtin_amdgcn_sched_barrier(0);
}

// ---------------- prep kernels ----------------

// h (fp32 [16384][800]) -> h_hi/h_lo (bf16 [16384][832], k-pad zeroed)
__global__ __launch_bounds__(256) void hsplit_kernel(const float* __restrict__ x,
                                                     u16* __restrict__ hi,
                                                     u16* __restrict__ lo) {
    int idx = blockIdx.x * 256 + threadIdx.x;   // 16384*208 groups of 4 cols
    int rw = idx / 208, g = idx - rw * 208;
    ushort4 hv = {0, 0, 0, 0}, lv = {0, 0, 0, 0};
    if (g < 200) {
        float4 v = *(const float4*)(x + (long)rw * DD + g * 4);
        u16 h0 = f2bf(v.x), h1 = f2bf(v.y), h2 = f2bf(v.z), h3 = f2bf(v.w);
        hv = (ushort4){h0, h1, h2, h3};
        lv = (ushort4){f2bf(v.x - bf2f(h0)), f2bf(v.y - bf2f(h1)),
                       f2bf(v.z - bf2f(h2)), f2bf(v.w - bf2f(h3))};
    }
    *(ushort4*)(hi + (long)rw * KP + g * 4) = hv;
    *(ushort4*)(lo + (long)rw * KP + g * 4) = lv;
}

// W (fp32 [800][800]) -> Wt_hi/Wt_lo (bf16 [1024][832], transposed, pads zeroed)
__global__ __launch_bounds__(256) void wsplit_kernel(const float* __restrict__ W,
                                                     u16* __restrict__ hi,
                                                     u16* __restrict__ lo) {
    int idx = blockIdx.x * 256 + threadIdx.x;   // 1024*832
    int e = idx / KP, d = idx - e * KP;
    float v = (e < DD && d < DD) ? W[(long)d * DD + e] : 0.f;
    u16 h = f2bf(v);
    hi[idx] = h;
    lo[idx] = f2bf(v - bf2f(h));
}

// h_hi (bf16 [8][2048][832]) -> hT (bf16 [8][1024][2048], pad rows zeroed)
__global__ void transpose_kernel(const u16* __restrict__ h_hi, u16* __restrict__ hT) {
    __shared__ u16 tile[32][33];
    int b = blockIdx.z;
    int t0 = blockIdx.x * 32, d0 = blockIdx.y * 32;
    int lx = threadIdx.x, ly = threadIdx.y;
    for (int i = ly; i < 32; i += 8) {
        int d = d0 + lx;
        tile[i][lx] = (d < DD) ? h_hi[((long)b * SS + t0 + i) * KP + d] : (u16)0;
    }
    __syncthreads();
    for (int i = ly; i < 32; i += 8) {
        hT[((long)b * 1024 + d0 + i) * SS + t0 + lx] = tile[lx][i];
    }
}

// ---------------- softmax (one block per row, in-place fp32 -> bf16 attn) ------

__global__ __launch_bounds__(256) void softmax_kernel(float* __restrict__ scores) {
    const long row = blockIdx.x;
    float* p = scores + row * (long)SS;
    const int tid = threadIdx.x;
    const int lane = tid & 63, wid = tid >> 6;
    __shared__ float red[8];

    float v[8];
    float mx = -3.4e38f;
#pragma unroll
    for (int j = 0; j < 8; ++j) { v[j] = p[tid + 256 * j]; mx = fmaxf(mx, v[j]); }
#pragma unroll
    for (int o = 32; o; o >>= 1) mx = fmaxf(mx, __shfl_xor(mx, o, 64));
    if (lane == 0) red[wid] = mx;
    __syncthreads();
    mx = fmaxf(fmaxf(red[0], red[1]), fmaxf(red[2], red[3]));

    float sum = 0.f;
#pragma unroll
    for (int j = 0; j < 8; ++j) { v[j] = __expf(v[j] - mx); sum += v[j]; }
#pragma unroll
    for (int o = 32; o; o >>= 1) sum += __shfl_xor(sum, o, 64);
    if (lane == 0) red[4 + wid] = sum;
    __syncthreads();
    const float inv = 1.f / (red[4] + red[5] + red[6] + red[7]);

    u16* attn = (u16*)p;
#pragma unroll
    for (int j = 0; j < 8; ++j) attn[tid + 256 * j] = f2bf(v[j] * inv);
}

// ---------------- deep-pipelined GEMM: C[m][n] = sum_k A[m][k]*B[n][k] ----------
// BM x 256 tile, BK=64, 512 threads (8 waves, 2M x 4N). M is batch-merged;
// when sB!=0, B/batch = m0>>11. SPLIT3: K' = 3K via per-K-tile variant
// (Ahi,Bhi)/(Ahi,Blo)/(Alo,Bhi). LDS per operand: [2 dbuf][2 ksub][frags][512u16]
// cells of 1KB; fragment read = cell base + lane*16B (conflict-free);
// global_load_lds dest linear, source permuted to match (rule #21).
// Schedule (BM=256, 4 phases/K-tile): stage bursts (4 loads) at phases 0,2 with
// 6-phase lead; vmcnt(8) fences only at phases 1,3 (counted, never 0 mid-loop).
// BM=128: 2 phases/K-tile, 3-load bursts each phase, vmcnt(6) fences.

template <int BM, int SPLIT3, int SPLIT_OUT, int NGUARD>
__global__ __launch_bounds__(512, 2) void gemm8(
    const u16* __restrict__ Ahi, const u16* __restrict__ Alo, int lda,
    const u16* __restrict__ Bhi, const u16* __restrict__ Blo, long sB, int ldb,
    float* __restrict__ C, u16* __restrict__ Chi, u16* __restrict__ Clo,
    int ldc, int Nlim, int Nbuf, int ksteps, int gmt) {
    constexpr int ABUF = BM * 64;          // u16 per A dbuf
    constexpr int MFR = (BM == 256) ? 8 : 4;
    extern __shared__ u16 smem[];
    u16* lsA = smem;                       // [2][ABUF]
    u16* lsB = smem + 2 * ABUF;            // [2][16384]

    const int tid = threadIdx.x;
    const int lane = tid & 63, wid = tid >> 6;
    const int wm = wid >> 2, wn = wid & 3;

    // bijective XCD remap (m204) on linearized grid, mt-fastest
    const int nwg = gridDim.x;
    const int orig = blockIdx.x;
    const int q = nwg >> 3, r = nwg & 7;
    const int xcd = orig & 7;
    const int wg = (xcd < r ? xcd * (q + 1) : r * (q + 1) + (xcd - r) * q) + (orig >> 3);
    const int m0 = (wg % gmt) * BM;
    const int n0 = (wg / gmt) * 256;

    const long boff = sB ? (long)(m0 >> 11) * sB : 0;
    const u16* Bh = Bhi + boff;
    const u16* Bl = SPLIT3 ? (Blo + boff) : nullptr;

    const int rlane = lane & 15;
    const int l8 = lane * 8;

    f32x4 acc[MFR][4];
#pragma unroll
    for (int i = 0; i < MFR; ++i)
#pragma unroll
        for (int j = 0; j < 4; ++j) acc[i][j] = (f32x4){0.f, 0.f, 0.f, 0.f};

    auto stage = [&](int t, int s) {
        int kk = SPLIT3 ? (t / 3) : t;
        int v = SPLIT3 ? (t - kk * 3) : 0;
        const u16* As = (SPLIT3 && v == 2) ? Alo : Ahi;
        const u16* Bs = (SPLIT3 && v == 1) ? Bl : Bh;
        const int d = t & 1;
        const int kg = kk * 64 + s * 32 + (lane >> 4) * 8;
        u16* aB = lsA + d * ABUF + s * (BM / 16) * 512;
        u16* bB = lsB + d * 16384 + s * 16 * 512;
        if (BM == 256) {
            const int f = 2 * wid;
            gload16(As + (long)(m0 + f * 16 + rlane) * lda + kg, aB + f * 512);
            gload16(As + (long)(m0 + f * 16 + 16 + rlane) * lda + kg, aB + (f + 1) * 512);
            gload16(Bs + (long)(n0 + f * 16 + rlane) * ldb + kg, bB + f * 512);
            gload16(Bs + (long)(n0 + f * 16 + 16 + rlane) * ldb + kg, bB + (f + 1) * 512);
        } else {
            gload16(As + (long)(m0 + wid * 16 + rlane) * lda + kg, aB + wid * 512);
            const int f = 2 * wid;
            gload16(Bs + (long)(n0 + f * 16 + rlane) * ldb + kg, bB + f * 512);
            gload16(Bs + (long)(n0 + f * 16 + 16 + rlane) * ldb + kg, bB + (f + 1) * 512);
        }
    };

    // prologue: tiles 0.s0, 0.s1, 1.s0 staged; fence covers 0.s0
    stage(0, 0);
    stage(0, 1);
    if (ksteps > 1) {
        stage(1, 0);
        if (BM == 256) { VMF(8); } else { VMF(6); }
    } else {
        if (BM == 256) { VMF(4); } else { VMF(3); }
    }
    barrier_pin();

    if constexpr (BM == 256) {
        bf16x8 a[8], b0, b1;
        for (int t = 0; t < ksteps; ++t) {
            const int d = t & 1;
            const bool h1 = (t + 1 < ksteps), h2 = (t + 2 < ksteps);
            const u16* aBuf = lsA + d * ABUF;
            const u16* bBuf = lsB + d * 16384;
            // phase 0: s0, B01; issue (t+1).s1
            {
                const u16* ap = aBuf + (wm * 8) * 512 + l8;
#pragma unroll
                for (int i = 0; i < 8; ++i) a[i] = *(const bf16x8*)(ap + i * 512);
                const u16* bp = bBuf + (wn * 4) * 512 + l8;
                b0 = *(const bf16x8*)bp;
                b1 = *(const bf16x8*)(bp + 512);
                if (h1) stage(t + 1, 1);
                barrier_pin();
                __builtin_amdgcn_s_setprio(1);
#pragma unroll
                for (int i = 0; i < 8; ++i) {
                    acc[i][0] = MFMA16(a[i], b0, acc[i][0]);
                    acc[i][1] = MFMA16(a[i], b1, acc[i][1]);
                }
                __builtin_amdgcn_s_setprio(0);
                barrier_pin();
            }
            // phase 1: s0, B23; fence covers t.s1
            {
                const u16* bp = bBuf + (wn * 4 + 2) * 512 + l8;
                b0 = *(const bf16x8*)bp;
                b1 = *(const bf16x8*)(bp + 512);
                barrier_pin();
                __builtin_amdgcn_s_setprio(1);
#pragma unroll
                for (int i = 0; i < 8; ++i) {
                    acc[i][2] = MFMA16(a[i], b0, acc[i][2]);
                    acc[i][3] = MFMA16(a[i], b1, acc[i][3]);
                }
                __builtin_amdgcn_s_setprio(0);
                if (h1) { VMF(8); } else { VMF(0); }
                barrier_pin();
            }
            // phase 2: s1, B01; issue (t+2).s0
            {
                const u16* ap = aBuf + (16 + wm * 8) * 512 + l8;
#pragma unroll
                for (int i = 0; i < 8; ++i) a[i] = *(const bf16x8*)(ap + i * 512);
                const u16* bp = bBuf + (16 + wn * 4) * 512 + l8;
                b0 = *(const bf16x8*)bp;
                b1 = *(const bf16x8*)(bp + 512);
                if (h2) stage(t + 2, 0);
                barrier_pin();
                __builtin_amdgcn_s_setprio(1);
#pragma unroll
                for (int i = 0; i < 8; ++i) {
                    acc[i][0] = MFMA16(a[i], b0, acc[i][0]);
                    acc[i][1] = MFMA16(a[i], b1, acc[i][1]);
                }
                __builtin_amdgcn_s_setprio(0);
                barrier_pin();
            }
            // phase 3: s1, B23; fence covers (t+1).s0
            {
                const u16* bp = bBuf + (16 + wn * 4 + 2) * 512 + l8;
                b0 = *(const bf16x8*)bp;
                b1 = *(const bf16x8*)(bp + 512);
                barrier_pin();
                __builtin_amdgcn_s_setprio(1);
#pragma unroll
                for (int i = 0; i < 8; ++i) {
                    acc[i][2] = MFMA16(a[i], b0, acc[i][2]);
                    acc[i][3] = MFMA16(a[i], b1, acc[i][3]);
                }
                __builtin_amdgcn_s_setprio(0);
                if (h1) {
                    if (h2) { VMF(8); } else { VMF(4); }
                }
                barrier_pin();
            }
        }
    } else {
        bf16x8 a[4], b[4];
        for (int t = 0; t < ksteps; ++t) {
            const int d = t & 1;
            const bool h1 = (t + 1 < ksteps), h2 = (t + 2 < ksteps);
            const u16* aBuf = lsA + d * ABUF;
            const u16* bBuf = lsB + d * 16384;
            // phase 0: s0; issue (t+1).s1; fence covers t.s1
            {
                const u16* ap = aBuf + (wm * 4) * 512 + l8;
#pragma unroll
                for (int i = 0; i < 4; ++i) a[i] = *(const bf16x8*)(ap + i * 512);
                const u16* bp = bBuf + (wn * 4) * 512 + l8;
#pragma unroll
                for (int j = 0; j < 4; ++j) b[j] = *(const bf16x8*)(bp + j * 512);
                if (h1) stage(t + 1, 1);
                barrier_pin();
                __builtin_amdgcn_s_setprio(1);
#pragma unroll
                for (int i = 0; i < 4; ++i)
#pragma unroll
                    for (int j = 0; j < 4; ++j) acc[i][j] = MFMA16(a[i], b[j], acc[i][j]);
                __builtin_amdgcn_s_setprio(0);
                if (h1) { VMF(6); } else { VMF(0); }
                barrier_pin();
            }
            // phase 1: s1; issue (t+2).s0; fence covers (t+1).s0
            {
                const u16* ap = aBuf + (8 + wm * 4) * 512 + l8;
#pragma unroll
                for (int i = 0; i < 4; ++i) a[i] = *(const bf16x8*)(ap + i * 512);
                const u16* bp = bBuf + (16 + wn * 4) * 512 + l8;
#pragma unroll
                for (int j = 0; j < 4; ++j) b[j] = *(const bf16x8*)(bp + j * 512);
                if (h2) stage(t + 2, 0);
                barrier_pin();
                __builtin_amdgcn_s_setprio(1);
#pragma unroll
                for (int i = 0; i < 4; ++i)
#pragma unroll
                    for (int j = 0; j < 4; ++j) acc[i][j] = MFMA16(a[i], b[j], acc[i][j]);
                __builtin_amdgcn_s_setprio(0);
                if (h1) {
                    if (h2) { VMF(6); } else { VMF(3); }
                }
                barrier_pin();
            }
        }
    }

    // epilogue: C/D layout col=lane&15, row=(lane>>4)*4+reg (R1-verified convention)
    const int crow = m0 + wm * (BM / 2) + (lane >> 4) * 4;
    const int ccol = n0 + wn * 64 + rlane;
#pragma unroll
    for (int i = 0; i < MFR; ++i) {
#pragma unroll
        for (int j = 0; j < 4; ++j) {
            const int nn = ccol + j * 16;
            if (NGUARD && nn >= Nbuf) continue;
#pragma unroll
            for (int rr = 0; rr < 4; ++rr) {
                const int mm = crow + i * 16 + rr;
                const long off = (long)mm * ldc + nn;
                float v = acc[i][j][rr];
                if (NGUARD && nn >= Nlim) v = 0.f;
                if (SPLIT_OUT) {
                    u16 hh = f2bf(v);
                    Chi[off] = hh;
                    Clo[off] = f2bf(v - bf2f(hh));
                } else {
                    C[off] = v;
                }
            }
        }
    }
}

// ---------------- host ----------------

extern "C" void kernel_launch(void* const* d_in, const int* in_sizes, int n_in,
                              void* d_out, int out_size, void* d_ws, size_t ws_size,
                              hipStream_t stream) {
    const float* h = (const float*)d_in[0];
    const float* W = (const float*)d_in[1];
    float* out = (float*)d_out;

    char* ws = (char*)d_ws;
    size_t off = 0;
    auto alloc = [&](size_t bytes) -> void* {
        void* p = ws + off;
        off += (bytes + 255) & ~(size_t)255;
        return p;
    };
    const size_t MD = (size_t)M1 * KP;
    u16* h_hi  = (u16*)alloc(MD * 2);
    u16* h_lo  = (u16*)alloc(MD * 2);
    u16* hW_hi = (u16*)alloc(MD * 2);
    u16* hW_lo = (u16*)alloc(MD * 2);
    u16* hT    = (u16*)alloc((size_t)BB * 1024 * SS * 2);
    u16* Wt_hi = (u16*)alloc((size_t)1024 * KP * 2);
    u16* Wt_lo = (u16*)alloc((size_t)1024 * KP * 2);
    float* scores = (float*)alloc((size_t)4 * SS * SS * 4);   // 4-batch chunk

    // raise dynamic-LDS cap (idempotent, not a stream op -> capture-safe)
    hipFuncSetAttribute(reinterpret_cast<const void*>(&gemm8<256, 1, 1, 1>),
                        hipFuncAttributeMaxDynamicSharedMemorySize, 131072);
    hipFuncSetAttribute(reinterpret_cast<const void*>(&gemm8<256, 1, 0, 0>),
                        hipFuncAttributeMaxDynamicSharedMemorySize, 131072);
    hipFuncSetAttribute(reinterpret_cast<const void*>(&gemm8<128, 0, 0, 1>),
                        hipFuncAttributeMaxDynamicSharedMemorySize, 98304);

    // prep
    hsplit_kernel<<<dim3(16384 * 208 / 256), dim3(256), 0, stream>>>(h, h_hi, h_lo);
    wsplit_kernel<<<dim3(1024 * KP / 256), dim3(256), 0, stream>>>(W, Wt_hi, Wt_lo);
    transpose_kernel<<<dim3(SS / 32, 32, BB), dim3(32, 8), 0, stream>>>(h_hi, hT);

    // GEMM1: hW = h @ W  (M=16384, N=1024pad, K'=39) split-out, zero k-pad cols
    gemm8<256, 1, 1, 1><<<dim3(256), dim3(512), 131072, stream>>>(
        h_hi, h_lo, KP,
        Wt_hi, Wt_lo, 0L, KP,
        nullptr, hW_hi, hW_lo,
        KP, DD, KP, 39, 64);

    for (int b0 = 0; b0 < BB; b0 += 4) {
        const long aoff = (long)b0 * SS * KP;
        // GEMM2: scores = hW @ h^T  (chunk M=8192 m-merged, N=2048/batch, K'=39)
        gemm8<256, 1, 0, 0><<<dim3(256), dim3(512), 131072, stream>>>(
            hW_hi + aoff, hW_lo + aoff, KP,
            h_hi + aoff, h_lo + aoff, (long)SS * KP, KP,
            scores, nullptr, nullptr,
            SS, SS, SS, 39, 32);
        // softmax rows -> bf16 attn in place (pitch 4096 u16)
        softmax_kernel<<<dim3(4 * SS), dim3(256), 0, stream>>>(scores);
        // PV: out = attn @ h  (chunk M=8192, N=1024pad, K=2048, BM=128)
        gemm8<128, 0, 0, 1><<<dim3(256), dim3(512), 98304, stream>>>(
            (const u16*)scores, nullptr, SS * 2,
            hT + (long)b0 * 1024 * SS, nullptr, (long)1024 * SS, SS,
            out + (long)b0 * SS * DD, nullptr, nullptr,
            DD, DD, DD, 32, 64);
    }
}

// Round 5
// 437.790 us; speedup vs baseline: 1.2974x; 1.0349x over previous
//
#include <hip/hip_runtime.h>
#include <hip/hip_bf16.h>
#include <stdint.h>

// ProjectiveAttention: out = softmax(h @ W @ h^T) @ h
// B=8, S=2048, D=800, all fp32 in/out.
// R4: deep-pipelined 256x256xBK64 8-wave GEMM template, split3-as-K-extended.
// R5: m201-faithful fine interleave — each phase stages exactly ONE small
// burst of tile t+1; counted fences vmcnt(4)/vmcnt(3) at K-tile cadence
// (never 0 mid-loop). Was: bunched 4-load bursts + vmcnt(8) => 770 TF/31% util.

#define BB 8
#define SS 2048
#define DD 800
#define KP 832            // K padded to 13*64
#define M1 (BB*SS)        // 16384

typedef unsigned short u16;
typedef __attribute__((ext_vector_type(8))) short bf16x8;
typedef __attribute__((ext_vector_type(4))) float f32x4;

#define MFMA16(A, B, C) __builtin_amdgcn_mfma_f32_16x16x32_bf16(A, B, C, 0, 0, 0)
#define VMF(N) asm volatile("s_waitcnt vmcnt(" #N ")" ::: "memory")

__device__ __forceinline__ u16 f2bf(float x) {
    uint32_t u = __float_as_uint(x);
    uint32_t r = (u + 0x7fffu + ((u >> 16) & 1u)) >> 16;  // RTN-even
    return (u16)r;
}
__device__ __forceinline__ float bf2f(u16 h) {
    return __uint_as_float(((uint32_t)h) << 16);
}
__device__ __forceinline__ void gload16(const void* g, void* l) {
    __builtin_amdgcn_global_load_lds((__attribute__((address_space(1))) void*)g,
                                     (__attribute__((address_space(3))) void*)l,
                                     16, 0, 0);
}
__device__ __forceinline__ void barrier_pin() {
    __builtin_amdgcn_sched_barrier(0);
    __builtin_amdgcn_s_barrier();
    __builtin_amdgcn_sched_barrier(0);
}

// ---------------- prep kernels ----------------

// h (fp32 [16384][800]) -> h_hi/h_lo (bf16 [16384][832], k-pad zeroed)
__global__ __launch_bounds__(256) void hsplit_kernel(const float* __restrict__ x,
                                                     u16* __restrict__ hi,
                                                     u16* __restrict__ lo) {
    int idx = blockIdx.x * 256 + threadIdx.x;   // 16384*208 groups of 4 cols
    int rw = idx / 208, g = idx - rw * 208;
    ushort4 hv = {0, 0, 0, 0}, lv = {0, 0, 0, 0};
    if (g < 200) {
        float4 v = *(const float4*)(x + (long)rw * DD + g * 4);
        u16 h0 = f2bf(v.x), h1 = f2bf(v.y), h2 = f2bf(v.z), h3 = f2bf(v.w);
        hv = (ushort4){h0, h1, h2, h3};
        lv = (ushort4){f2bf(v.x - bf2f(h0)), f2bf(v.y - bf2f(h1)),
                       f2bf(v.z - bf2f(h2)), f2bf(v.w - bf2f(h3))};
    }
    *(ushort4*)(hi + (long)rw * KP + g * 4) = hv;
    *(ushort4*)(lo + (long)rw * KP + g * 4) = lv;
}

// W (fp32 [800][800]) -> Wt_hi/Wt_lo (bf16 [1024][832], transposed, pads zeroed)
__global__ __launch_bounds__(256) void wsplit_kernel(const float* __restrict__ W,
                                                     u16* __restrict__ hi,
                                                     u16* __restrict__ lo) {
    int idx = blockIdx.x * 256 + threadIdx.x;   // 1024*832
    int e = idx / KP, d = idx - e * KP;
    float v = (e < DD && d < DD) ? W[(long)d * DD + e] : 0.f;
    u16 h = f2bf(v);
    hi[idx] = h;
    lo[idx] = f2bf(v - bf2f(h));
}

// h_hi (bf16 [8][2048][832]) -> hT (bf16 [8][1024][2048], pad rows zeroed)
__global__ void transpose_kernel(const u16* __restrict__ h_hi, u16* __restrict__ hT) {
    __shared__ u16 tile[32][33];
    int b = blockIdx.z;
    int t0 = blockIdx.x * 32, d0 = blockIdx.y * 32;
    int lx = threadIdx.x, ly = threadIdx.y;
    for (int i = ly; i < 32; i += 8) {
        int d = d0 + lx;
        tile[i][lx] = (d < DD) ? h_hi[((long)b * SS + t0 + i) * KP + d] : (u16)0;
    }
    __syncthreads();
    for (int i = ly; i < 32; i += 8) {
        hT[((long)b * 1024 + d0 + i) * SS + t0 + lx] = tile[lx][i];
    }
}

// ---------------- softmax (one block per row, in-place fp32 -> bf16 attn) ------

__global__ __launch_bounds__(256) void softmax_kernel(float* __restrict__ scores) {
    const long row = blockIdx.x;
    float* p = scores + row * (long)SS;
    const int tid = threadIdx.x;
    const int lane = tid & 63, wid = tid >> 6;
    __shared__ float red[8];

    float v[8];
    float mx = -3.4e38f;
#pragma unroll
    for (int j = 0; j < 8; ++j) { v[j] = p[tid + 256 * j]; mx = fmaxf(mx, v[j]); }
#pragma unroll
    for (int o = 32; o; o >>= 1) mx = fmaxf(mx, __shfl_xor(mx, o, 64));
    if (lane == 0) red[wid] = mx;
    __syncthreads();
    mx = fmaxf(fmaxf(red[0], red[1]), fmaxf(red[2], red[3]));

    float sum = 0.f;
#pragma unroll
    for (int j = 0; j < 8; ++j) { v[j] = __expf(v[j] - mx); sum += v[j]; }
#pragma unroll
    for (int o = 32; o; o >>= 1) sum += __shfl_xor(sum, o, 64);
    if (lane == 0) red[4 + wid] = sum;
    __syncthreads();
    const float inv = 1.f / (red[4] + red[5] + red[6] + red[7]);

    u16* attn = (u16*)p;
#pragma unroll
    for (int j = 0; j < 8; ++j) attn[tid + 256 * j] = f2bf(v[j] * inv);
}

// ---------------- deep-pipelined GEMM: C[m][n] = sum_k A[m][k]*B[n][k] ----------
// BM x 256 tile, BK=64 (2 ksubs of 32), 512 threads (8 waves). M batch-merged;
// when sB!=0, batch = m0>>11. SPLIT3: K'=3K via per-K-tile variant
// (Ahi,Bhi)/(Ahi,Blo)/(Alo,Bhi). LDS: per operand [2 dbuf][2 ksub][cells][512u16],
// cell = one 16x32 fragment in lane-order; fragment read = cell + lane*16B
// (conflict-free, R2-verified 0 conflicts); gload dest linear, source permuted.
//
// Schedule (m201-faithful): BM=256 -> 4 phases/K-tile, 16 MFMA each; every
// phase stages ONE 2-instr burst of tile t+1 ({A.s0,B.s0,A.s1,B.s1} spread);
// fences vmcnt(4) at phases 1,3 only (oldest 4 = data next 2 phases read).
// BM=128 -> 2 phases/K-tile, 3-instr bursts, fences vmcnt(3) each phase.

template <int BM, int SPLIT3, int SPLIT_OUT, int NGUARD>
__global__ __launch_bounds__(512, 2) void gemm8(
    const u16* __restrict__ Ahi, const u16* __restrict__ Alo, int lda,
    const u16* __restrict__ Bhi, const u16* __restrict__ Blo, long sB, int ldb,
    float* __restrict__ C, u16* __restrict__ Chi, u16* __restrict__ Clo,
    int ldc, int Nlim, int Nbuf, int ksteps, int gmt) {
    constexpr int ABUF = BM * 64;          // u16 per A dbuf
    constexpr int AS = (BM / 16) * 512;    // u16 per A ksub region
    constexpr int MFR = (BM == 256) ? 8 : 4;
    extern __shared__ u16 smem[];
    u16* lsA = smem;                       // [2][ABUF]
    u16* lsB = smem + 2 * ABUF;            // [2][16384]

    const int tid = threadIdx.x;
    const int lane = tid & 63, wid = tid >> 6;
    const int wm = wid >> 2, wn = wid & 3;

    // bijective XCD remap (m204) on linearized grid, mt-fastest
    const int nwg = gridDim.x;
    const int orig = blockIdx.x;
    const int q = nwg >> 3, r = nwg & 7;
    const int xcd = orig & 7;
    const int wg = (xcd < r ? xcd * (q + 1) : r * (q + 1) + (xcd - r) * q) + (orig >> 3);
    const int m0 = (wg % gmt) * BM;
    const int n0 = (wg / gmt) * 256;

    const long boff = sB ? (long)(m0 >> 11) * sB : 0;
    const u16* Bh = Bhi + boff;
    const u16* Bl = SPLIT3 ? (Blo + boff) : nullptr;

    const int rlane = lane & 15;
    const int l8 = lane * 8;
    const int kl = (lane >> 4) * 8;        // k sub-offset within staging source

    f32x4 acc[MFR][4];
#pragma unroll
    for (int i = 0; i < MFR; ++i)
#pragma unroll
        for (int j = 0; j < 4; ++j) acc[i][j] = (f32x4){0.f, 0.f, 0.f, 0.f};

    // resolve K'-tile t -> (k-block base, A-part, B-part)
    auto resolve = [&](int t, const u16*& As, const u16*& Bs, int& kb) {
        if (SPLIT3) {
            int kk = t / 3, v = t - kk * 3;
            As = (v == 2) ? Alo : Ahi;
            Bs = (v == 1) ? Bl : Bh;
            kb = kk * 64;
        } else {
            As = Ahi; Bs = Bh; kb = t * 64;
        }
    };

    // one staging burst: A-cells or B-cells of one ksub s of tile t (dbuf d)
    auto stageA = [&](const u16* As, int kb, int s, int d) {
        const int kg = kb + s * 32 + kl;
        u16* aB = lsA + d * ABUF + s * AS;
        if (BM == 256) {
            const int f = 2 * wid;
            gload16(As + (long)(m0 + f * 16 + rlane) * lda + kg, aB + f * 512);
            gload16(As + (long)(m0 + f * 16 + 16 + rlane) * lda + kg, aB + (f + 1) * 512);
        } else {
            gload16(As + (long)(m0 + wid * 16 + rlane) * lda + kg, aB + wid * 512);
        }
    };
    auto stageB = [&](const u16* Bs, int kb, int s, int d) {
        const int kg = kb + s * 32 + kl;
        u16* bB = lsB + d * 16384 + s * 8192;
        const int f = 2 * wid;
        gload16(Bs + (long)(n0 + f * 16 + rlane) * ldb + kg, bB + f * 512);
        gload16(Bs + (long)(n0 + f * 16 + 16 + rlane) * ldb + kg, bB + (f + 1) * 512);
    };

    // prologue: stage all of tile 0; wait for its s0 (oldest burst pair)
    {
        const u16 *As, *Bs; int kb;
        resolve(0, As, Bs, kb);
        stageA(As, kb, 0, 0);
        stageB(Bs, kb, 0, 0);
        stageA(As, kb, 1, 0);
        stageB(Bs, kb, 1, 0);
        if (BM == 256) { VMF(4); } else { VMF(3); }
    }
    barrier_pin();

    if constexpr (BM == 256) {
        bf16x8 a[8], b0, b1;
        for (int t = 0; t < ksteps; ++t) {
            const int d = t & 1;
            const bool h1 = (t + 1 < ksteps);
            const u16* aBuf = lsA + d * ABUF;
            const u16* bBuf = lsB + d * 16384;
            const u16 *As1, *Bs1; int kb1;
            resolve(h1 ? t + 1 : t, As1, Bs1, kb1);
            // phase 0: a[8]@s0 + b01@s0; stage (t+1).A.s0
            {
                const u16* ap = aBuf + wm * 4096 + l8;
#pragma unroll
                for (int i = 0; i < 8; ++i) a[i] = *(const bf16x8*)(ap + i * 512);
                const u16* bp = bBuf + wn * 2048 + l8;
                b0 = *(const bf16x8*)bp;
                b1 = *(const bf16x8*)(bp + 512);
                if (h1) stageA(As1, kb1, 0, d ^ 1);
                barrier_pin();
                __builtin_amdgcn_s_setprio(1);
#pragma unroll
                for (int i = 0; i < 8; ++i) {
                    acc[i][0] = MFMA16(a[i], b0, acc[i][0]);
                    acc[i][1] = MFMA16(a[i], b1, acc[i][1]);
                }
                __builtin_amdgcn_s_setprio(0);
                barrier_pin();
            }
            // phase 1: b23@s0; stage (t+1).B.s0; fence covers t's s1 data
            {
                const u16* bp = bBuf + wn * 2048 + 1024 + l8;
                b0 = *(const bf16x8*)bp;
                b1 = *(const bf16x8*)(bp + 512);
                if (h1) stageB(Bs1, kb1, 0, d ^ 1);
                barrier_pin();
                __builtin_amdgcn_s_setprio(1);
#pragma unroll
                for (int i = 0; i < 8; ++i) {
                    acc[i][2] = MFMA16(a[i], b0, acc[i][2]);
                    acc[i][3] = MFMA16(a[i], b1, acc[i][3]);
                }
                __builtin_amdgcn_s_setprio(0);
                if (h1) { VMF(4); } else { VMF(0); }
                barrier_pin();
            }
            // phase 2: a[8]@s1 + b01@s1; stage (t+1).A.s1
            {
                const u16* ap = aBuf + AS + wm * 4096 + l8;
#pragma unroll
                for (int i = 0; i < 8; ++i) a[i] = *(const bf16x8*)(ap + i * 512);
                const u16* bp = bBuf + 8192 + wn * 2048 + l8;
                b0 = *(const bf16x8*)bp;
                b1 = *(const bf16x8*)(bp + 512);
                if (h1) stageA(As1, kb1, 1, d ^ 1);
                barrier_pin();
                __builtin_amdgcn_s_setprio(1);
#pragma unroll
                for (int i = 0; i < 8; ++i) {
                    acc[i][0] = MFMA16(a[i], b0, acc[i][0]);
                    acc[i][1] = MFMA16(a[i], b1, acc[i][1]);
                }
                __builtin_amdgcn_s_setprio(0);
                barrier_pin();
            }
            // phase 3: b23@s1; stage (t+1).B.s1; fence covers (t+1) s0 data
            {
                const u16* bp = bBuf + 8192 + wn * 2048 + 1024 + l8;
                b0 = *(const bf16x8*)bp;
                b1 = *(const bf16x8*)(bp + 512);
                if (h1) stageB(Bs1, kb1, 1, d ^ 1);
                barrier_pin();
                __builtin_amdgcn_s_setprio(1);
#pragma unroll
                for (int i = 0; i < 8; ++i) {
                    acc[i][2] = MFMA16(a[i], b0, acc[i][2]);
                    acc[i][3] = MFMA16(a[i], b1, acc[i][3]);
                }
                __builtin_amdgcn_s_setprio(0);
                if (h1) { VMF(4); }
                barrier_pin();
            }
        }
    } else {
        bf16x8 a[4], b[4];
        for (int t = 0; t < ksteps; ++t) {
            const int d = t & 1;
            const bool h1 = (t + 1 < ksteps);
            const u16* aBuf = lsA + d * ABUF;
            const u16* bBuf = lsB + d * 16384;
            const u16 *As1, *Bs1; int kb1;
            resolve(h1 ? t + 1 : t, As1, Bs1, kb1);
            // phase 0 (s0): stage (t+1).{A,B}.s0; fence covers t's s1 data
            {
                const u16* ap = aBuf + wm * 2048 + l8;
#pragma unroll
                for (int i = 0; i < 4; ++i) a[i] = *(const bf16x8*)(ap + i * 512);
                const u16* bp = bBuf + wn * 2048 + l8;
#pragma unroll
                for (int j = 0; j < 4; ++j) b[j] = *(const bf16x8*)(bp + j * 512);
                if (h1) { stageA(As1, kb1, 0, d ^ 1); stageB(Bs1, kb1, 0, d ^ 1); }
                barrier_pin();
                __builtin_amdgcn_s_setprio(1);
#pragma unroll
                for (int i = 0; i < 4; ++i)
#pragma unroll
                    for (int j = 0; j < 4; ++j) acc[i][j] = MFMA16(a[i], b[j], acc[i][j]);
                __builtin_amdgcn_s_setprio(0);
                if (h1) { VMF(3); } else { VMF(0); }
                barrier_pin();
            }
            // phase 1 (s1): stage (t+1).{A,B}.s1; fence covers (t+1) s0 data
            {
                const u16* ap = aBuf + AS + wm * 2048 + l8;
#pragma unroll
                for (int i = 0; i < 4; ++i) a[i] = *(const bf16x8*)(ap + i * 512);
                const u16* bp = bBuf + 8192 + wn * 2048 + l8;
#pragma unroll
                for (int j = 0; j < 4; ++j) b[j] = *(const bf16x8*)(bp + j * 512);
                if (h1) { stageA(As1, kb1, 1, d ^ 1); stageB(Bs1, kb1, 1, d ^ 1); }
                barrier_pin();
                __builtin_amdgcn_s_setprio(1);
#pragma unroll
                for (int i = 0; i < 4; ++i)
#pragma unroll
                    for (int j = 0; j < 4; ++j) acc[i][j] = MFMA16(a[i], b[j], acc[i][j]);
                __builtin_amdgcn_s_setprio(0);
                if (h1) { VMF(3); }
                barrier_pin();
            }
        }
    }

    // epilogue: C/D layout col=lane&15, row=(lane>>4)*4+reg (R1-verified)
    const int crow = m0 + wm * (BM / 2) + (lane >> 4) * 4;
    const int ccol = n0 + wn * 64 + rlane;
#pragma unroll
    for (int i = 0; i < MFR; ++i) {
#pragma unroll
        for (int j = 0; j < 4; ++j) {
            const int nn = ccol + j * 16;
            if (NGUARD && nn >= Nbuf) continue;
#pragma unroll
            for (int rr = 0; rr < 4; ++rr) {
                const int mm = crow + i * 16 + rr;
                const long off = (long)mm * ldc + nn;
                float v = acc[i][j][rr];
                if (NGUARD && nn >= Nlim) v = 0.f;
                if (SPLIT_OUT) {
                    u16 hh = f2bf(v);
                    Chi[off] = hh;
                    Clo[off] = f2bf(v - bf2f(hh));
                } else {
                    C[off] = v;
                }
            }
        }
    }
}

// ---------------- host ----------------

extern "C" void kernel_launch(void* const* d_in, const int* in_sizes, int n_in,
                              void* d_out, int out_size, void* d_ws, size_t ws_size,
                              hipStream_t stream) {
    const float* h = (const float*)d_in[0];
    const float* W = (const float*)d_in[1];
    float* out = (float*)d_out;

    char* ws = (char*)d_ws;
    size_t off = 0;
    auto alloc = [&](size_t bytes) -> void* {
        void* p = ws + off;
        off += (bytes + 255) & ~(size_t)255;
        return p;
    };
    const size_t MD = (size_t)M1 * KP;
    u16* h_hi  = (u16*)alloc(MD * 2);
    u16* h_lo  = (u16*)alloc(MD * 2);
    u16* hW_hi = (u16*)alloc(MD * 2);
    u16* hW_lo = (u16*)alloc(MD * 2);
    u16* hT    = (u16*)alloc((size_t)BB * 1024 * SS * 2);
    u16* Wt_hi = (u16*)alloc((size_t)1024 * KP * 2);
    u16* Wt_lo = (u16*)alloc((size_t)1024 * KP * 2);
    float* scores = (float*)alloc((size_t)4 * SS * SS * 4);   // 4-batch chunk

    hipFuncSetAttribute(reinterpret_cast<const void*>(&gemm8<256, 1, 1, 1>),
                        hipFuncAttributeMaxDynamicSharedMemorySize, 131072);
    hipFuncSetAttribute(reinterpret_cast<const void*>(&gemm8<256, 1, 0, 0>),
                        hipFuncAttributeMaxDynamicSharedMemorySize, 131072);
    hipFuncSetAttribute(reinterpret_cast<const void*>(&gemm8<128, 0, 0, 1>),
                        hipFuncAttributeMaxDynamicSharedMemorySize, 98304);

    // prep
    hsplit_kernel<<<dim3(16384 * 208 / 256), dim3(256), 0, stream>>>(h, h_hi, h_lo);
    wsplit_kernel<<<dim3(1024 * KP / 256), dim3(256), 0, stream>>>(W, Wt_hi, Wt_lo);
    transpose_kernel<<<dim3(SS / 32, 32, BB), dim3(32, 8), 0, stream>>>(h_hi, hT);

    // GEMM1: hW = h @ W  (M=16384, N=1024pad, K'=39 tiles) split-out, zero k-pad
    gemm8<256, 1, 1, 1><<<dim3(256), dim3(512), 131072, stream>>>(
        h_hi, h_lo, KP,
        Wt_hi, Wt_lo, 0L, KP,
        nullptr, hW_hi, hW_lo,
        KP, DD, KP, 39, 64);

    for (int b0 = 0; b0 < BB; b0 += 4) {
        const long aoff = (long)b0 * SS * KP;
        // GEMM2: scores = hW @ h^T  (chunk M=8192 m-merged, N=2048/batch, K'=39)
        gemm8<256, 1, 0, 0><<<dim3(256), dim3(512), 131072, stream>>>(
            hW_hi + aoff, hW_lo + aoff, KP,
            h_hi + aoff, h_lo + aoff, (long)SS * KP, KP,
            scores, nullptr, nullptr,
            SS, SS, SS, 39, 32);
        // softmax rows -> bf16 attn in place (pitch 4096 u16)
        softmax_kernel<<<dim3(4 * SS), dim3(256), 0, stream>>>(scores);
        // PV: out = attn @ h  (chunk M=8192, N=1024pad, K=2048, BM=128)
        gemm8<128, 0, 0, 1><<<dim3(256), dim3(512), 98304, stream>>>(
            (const u16*)scores, nullptr, SS * 2,
            hT + (long)b0 * 1024 * SS, nullptr, (long)1024 * SS, SS,
            out + (long)b0 * SS * DD, nullptr, nullptr,
            DD, DD, DD, 32, 64);
    }
}